// Round 11
// baseline (43.981 us; speedup 1.0000x reference)
//
#include <hip/hip_runtime.h>

// TMoELayer: B=4,T=4096 -> N=16384 tokens, D_IN=1024, D_OUT=1024, E=8, TOP_K=2, R=16
// out[n][o] = sum_k (gate(n,e)*ce[n][r]) * routed[e][o][r], k = e*16+r
// Router logits via split-precision MFMA: W = Whi + Wlo/1024 (f16 pair),
// X = Xhi + Xlo (f16 pair) -> logit = Whi.Xhi + Whi.Xlo + (Wlo.Xhi + Wlo.Xlo)/1024.
// Operand tables pre-layouted in FRAGMENT ORDER: every hot-kernel global load is a
// contiguous 1KB wave-load.
constexpr float SCALING = 2.0f;  // alpha/r = 32/16

typedef __attribute__((ext_vector_type(8))) _Float16 half8;
typedef __attribute__((ext_vector_type(4))) _Float16 half4;
typedef __attribute__((ext_vector_type(4))) float    f32x4;

// ---------------- Kernel 0: prep (fragment-order tables), 80 blocks (finer grid
// than R10's 48: 1 store/thread -> more waves in flight for this latency-bound prep)
__global__ __launch_bounds__(256) void k0_prep(
    const float* __restrict__ routed, const float* __restrict__ compress,
    const float* __restrict__ w_route, _Float16* __restrict__ Btf,
    _Float16* __restrict__ A1f, _Float16* __restrict__ A2f)
{
  const int bid = blockIdx.x, tid = threadIdx.x;
  if (bid < 64){
    const int f = bid * 256 + tid;          // Btf fragment-slot 0..16383
    const int l = f & 63;
    const int rem = f >> 6;
    const int s = rem & 3, ot = rem >> 2;
    const int c15 = l & 15, kg = l >> 4;
    const int e  = 2 * s + (kg >> 1);
    const int r0 = (kg & 1) * 8;
    const float* src = routed + ((size_t)e * 1024 + ot * 16 + c15) * 16 + r0;
    float4 a = *(const float4*)(src);
    float4 b = *(const float4*)(src + 4);
    half8 h;
    h[0]=(_Float16)a.x; h[1]=(_Float16)a.y; h[2]=(_Float16)a.z; h[3]=(_Float16)a.w;
    h[4]=(_Float16)b.x; h[5]=(_Float16)b.y; h[6]=(_Float16)b.z; h[7]=(_Float16)b.w;
    *(half8*)(Btf + (size_t)f * 8) = h;
  } else if (bid < 72){
    const int t2 = (bid - 64) * 256 + tid;  // A2f fragment 0..2047
    const int l = t2 & 63, s = (t2 >> 6) & 7, wq = t2 >> 9;
    const int c15 = l & 15, kg = l >> 4;
    const float* src = compress + (size_t)c15 * 1024 + wq * 256 + s * 32 + kg * 8;
    float4 a = *(const float4*)(src);
    float4 b = *(const float4*)(src + 4);
    half8 h;
    h[0]=(_Float16)(SCALING*a.x); h[1]=(_Float16)(SCALING*a.y);
    h[2]=(_Float16)(SCALING*a.z); h[3]=(_Float16)(SCALING*a.w);
    h[4]=(_Float16)(SCALING*b.x); h[5]=(_Float16)(SCALING*b.y);
    h[6]=(_Float16)(SCALING*b.z); h[7]=(_Float16)(SCALING*b.w);
    *(half8*)(A2f + (size_t)t2 * 8) = h;
  } else {
    const int t3 = (bid - 72) * 256 + tid;  // A1f fragment 0..2047
    const int l = t3 & 63, s = (t3 >> 6) & 7, wq = t3 >> 9;
    const int c15 = l & 15, kg = l >> 4;
    const int row = (c15 < 8) ? c15 : (c15 - 8);
    const float* src = w_route + (size_t)row * 1024 + wq * 256 + s * 32 + kg * 8;
    float4 a = *(const float4*)(src);
    float4 b = *(const float4*)(src + 4);
    float ws[8] = {a.x, a.y, a.z, a.w, b.x, b.y, b.z, b.w};
    half8 h;
    #pragma unroll
    for (int j = 0; j < 8; ++j){
      _Float16 hi = (_Float16)ws[j];
      h[j] = (c15 < 8) ? hi : (_Float16)((ws[j] - (float)hi) * 1024.f);
    }
    *(half8*)(A1f + (size_t)t3 * 8) = h;
  }
}

// ---------------- Kernel 1: all-MFMA router + ce. 8-token tiles.
// LDS: xh/xl only (33 KB); the 12KB reduce buffers ALIAS the xh/xl region
// (live only after the last MFMA read; extra barrier covers the WAR hazard).
// -> 4 blocks/CU (was 3). A-fragments loaded in-loop (L2-resident) to keep
// VGPR under the 128 cap of __launch_bounds__(256,4).
__global__ __launch_bounds__(256, 4) void k_main(
    const float* __restrict__ x, const _Float16* __restrict__ A1f,
    const _Float16* __restrict__ A2f, _Float16* __restrict__ ce16,
    float4* __restrict__ gate_ws, int ntok)
{
  __shared__ __align__(16) char smem_raw[33024];   // 32.25 KB total
  _Float16* xh = (_Float16*)smem_raw;              // [8][1032]
  _Float16* xl = xh + 8 * 1032;                    // [8][1032]
  f32x4* p1 = (f32x4*)smem_raw;                    // [4][64] (aliases xh rows 0..1)
  f32x4* p2 = p1 + 256;                            // [4][64]
  f32x4* p3 = p1 + 512;                            // [4][64]
  const int tid = threadIdx.x, lane = tid & 63, wv = tid >> 6;
  const int c15 = lane & 15, kg = lane >> 4;
  const int n0 = blockIdx.x * 8;

  // ---- stage: wave wv loads rows wv*2, wv*2+1 contiguously, cvt hi/lo, LDS
  float4 xv[8];
  #pragma unroll
  for (int u = 0; u < 8; ++u){
    const int rr = u >> 2, qt = u & 3;
    xv[u] = *(const float4*)(x + (size_t)(n0 + wv * 2 + rr) * 1024 + qt * 256 + lane * 4);
  }
  #pragma unroll
  for (int u = 0; u < 8; ++u){
    const int rr = u >> 2, qt = u & 3;
    float xs[4] = {xv[u].x, xv[u].y, xv[u].z, xv[u].w};
    half4 hi, lo;
    #pragma unroll
    for (int q = 0; q < 4; ++q){
      _Float16 h = (_Float16)xs[q];
      hi[q] = h;
      lo[q] = (_Float16)(xs[q] - (float)h);
    }
    const int ho = (wv * 2 + rr) * 1032 + qt * 256 + lane * 4;
    *(half4*)&xh[ho] = hi;
    *(half4*)&xl[ho] = lo;
  }
  __syncthreads();

  // ---- MFMA: wave wv does K-quarter wv. 3 streams x 8 steps.
  // B cols 0..7 = tokens; cols 8..15 replicate row (c15&7) (discarded).
  f32x4 acc1 = {0.f,0.f,0.f,0.f};   // [Whi;Wlo] * Xhi
  f32x4 acc3 = {0.f,0.f,0.f,0.f};   // [Whi;Wlo] * Xlo
  f32x4 acc2 = {0.f,0.f,0.f,0.f};   // (2*compress) * Xhi
  #pragma unroll
  for (int s = 0; s < 8; ++s){
    half8 a1 = *(const half8*)(A1f + ((size_t)(wv * 8 + s) * 64 + lane) * 8);
    half8 a2 = *(const half8*)(A2f + ((size_t)(wv * 8 + s) * 64 + lane) * 8);
    const int xo = (c15 & 7) * 1032 + wv * 256 + s * 32 + kg * 8;
    half8 bhi = *(const half8*)&xh[xo];
    half8 blo = *(const half8*)&xl[xo];
    acc1 = __builtin_amdgcn_mfma_f32_16x16x32_f16(a1, bhi, acc1, 0, 0, 0);
    acc3 = __builtin_amdgcn_mfma_f32_16x16x32_f16(a1, blo, acc3, 0, 0, 0);
    acc2 = __builtin_amdgcn_mfma_f32_16x16x32_f16(a2, bhi, acc2, 0, 0, 0);
  }
  __syncthreads();   // all waves done READING xh/xl -> safe to overwrite with p*
  p1[wv * 64 + lane] = acc1;
  p3[wv * 64 + lane] = acc3;
  p2[wv * 64 + lane] = acc2;
  __syncthreads();
  if (wv != 0) return;

  f32x4 L = (p1[lane] + p1[64 + lane]) + (p1[128 + lane] + p1[192 + lane]);
  f32x4 X = (p3[lane] + p3[64 + lane]) + (p3[128 + lane] + p3[192 + lane]);
  f32x4 C = (p2[lane] + p2[64 + lane]) + (p2[128 + lane] + p2[192 + lane]);

  // ce store: D row = r = kg*4+v, col = token = c15 (only c15<8 valid)
  if (c15 < 8){
    half4 hce;
    hce[0]=(_Float16)C[0]; hce[1]=(_Float16)C[1];
    hce[2]=(_Float16)C[2]; hce[3]=(_Float16)C[3];
    *(half4*)(ce16 + (size_t)(n0 + c15) * 16 + kg * 4) = hce;
  }

  // logits: rows 0..7 (kg 0/1) pick up Wlo terms from rows 8..15 (lane+32)
  float lg[4];
  #pragma unroll
  for (int v = 0; v < 4; ++v){
    float wlo_xhi = __shfl_xor(L[v], 32, 64);
    float wlo_xlo = __shfl_xor(X[v], 32, 64);
    lg[v] = L[v] + X[v] + (wlo_xhi + wlo_xlo) * (1.0f / 1024.0f);
  }
  float l8[8];
  #pragma unroll
  for (int v = 0; v < 4; ++v){
    l8[v]     = lg[v];
    l8[4 + v] = __shfl_xor(lg[v], 16, 64);
  }
  if (lane < 8 && n0 + lane < ntok){
    float v0 = l8[0]; int e0 = 0;
    #pragma unroll
    for (int e = 1; e < 8; ++e) if (l8[e] > v0){ v0 = l8[e]; e0 = e; }
    float v1 = -3.402823466e38f; int e1 = 0;
    #pragma unroll
    for (int e = 0; e < 8; ++e) if (e != e0 && l8[e] > v1){ v1 = l8[e]; e1 = e; }
    float ex  = __expf(v1 - v0);
    float inv = 1.0f / (1.0f + ex);
    gate_ws[n0 + lane] = make_float4(__int_as_float(e0), __int_as_float(e1),
                                     inv, ex * inv);
  }
}

// ---------------- Kernel 2: out = (gate⊙ce) @ Bt^T — unchanged from R10
__global__ __launch_bounds__(256, 4) void k2_gemm(
    const _Float16* __restrict__ Btf, const _Float16* __restrict__ ce16,
    const float4* __restrict__ gate_ws, float* __restrict__ out, int ntok)
{
  __shared__ float tbuf[4][2][16][68];      // per-wave double-buffered, +16B row pad
  const int tid = threadIdx.x, lane = tid & 63, wv = tid >> 6;
  const int c15 = lane & 15, kg = lane >> 4;
  const int bn = blockIdx.x & 3;          // o-chunk of 256
  const int tg = blockIdx.x >> 2;         // token group of 64
  const int o0w = bn * 256 + wv * 64;

  half8 bt[4][4];
  #pragma unroll
  for (int nc = 0; nc < 4; ++nc){
    const int ot = bn * 16 + wv * 4 + nc;
    #pragma unroll
    for (int s = 0; s < 4; ++s)
      bt[nc][s] = *(const half8*)(Btf + ((size_t)(ot * 4 + s) * 64 + lane) * 8);
  }

  int tok = tg * 64 + c15;
  half8  ce_n = *(const half8*)(ce16 + (size_t)tok * 16 + (kg & 1) * 8);
  float4 gt_n = gate_ws[tok];

  #pragma unroll
  for (int i = 0; i < 4; ++i){
    half8 ce_c = ce_n;  float4 gt_c = gt_n;
    if (i < 3){
      const int tok2 = tg * 64 + (i + 1) * 16 + c15;
      ce_n = *(const half8*)(ce16 + (size_t)tok2 * 16 + (kg & 1) * 8);
      gt_n = gate_ws[tok2];
    }
    const int e0 = __float_as_int(gt_c.x), e1 = __float_as_int(gt_c.y);
    const int eb = kg >> 1;

    f32x4 acc[4] = {{0.f,0.f,0.f,0.f},{0.f,0.f,0.f,0.f},
                    {0.f,0.f,0.f,0.f},{0.f,0.f,0.f,0.f}};
    #pragma unroll
    for (int s = 0; s < 4; ++s){
      const int e = 2 * s + eb;           // expert of k-range [s*32+kg*8, +8)
      float sc = (e == e0) ? gt_c.z : ((e == e1) ? gt_c.w : 0.f);
      _Float16 sh = (_Float16)sc;
      half8 bfr;
      #pragma unroll
      for (int q = 0; q < 8; ++q) bfr[q] = ce_c[q] * sh;
      #pragma unroll
      for (int nc = 0; nc < 4; ++nc)
        acc[nc] = __builtin_amdgcn_mfma_f32_16x16x32_f16(bt[nc][s], bfr, acc[nc], 0, 0, 0);
    }
    #pragma unroll
    for (int nc = 0; nc < 4; ++nc)
      *(f32x4*)&tbuf[wv][i & 1][c15][nc * 16 + kg * 4] = acc[nc];
    const int n0i = tg * 64 + i * 16;
    #pragma unroll
    for (int p = 0; p < 4; ++p){
      const int row = p * 4 + kg;         // token-local row
      float4 v = *(const float4*)&tbuf[wv][i & 1][row][c15 * 4];
      *(float4*)(out + (size_t)(n0i + row) * 1024 + o0w + c15 * 4) = v;
    }
  }
}

extern "C" void kernel_launch(void* const* d_in, const int* in_sizes, int n_in,
                              void* d_out, int out_size, void* d_ws, size_t ws_size,
                              hipStream_t stream)
{
  const float* x        = (const float*)d_in[0];
  const float* w_route  = (const float*)d_in[1];
  const float* compress = (const float*)d_in[2];
  const float* routed   = (const float*)d_in[3];
  float* out = (float*)d_out;

  const int ntok = in_sizes[0] / 1024;   // 16384 (B*T)
  char* ws = (char*)d_ws;
  _Float16* ce16    = (_Float16*)ws;                               // ntok*16 f16  (512 KB)
  float4*   gate_ws = (float4*)(ws + (size_t)ntok * 32);           // ntok*16 B    (256 KB)
  _Float16* Btf     = (_Float16*)(ws + (size_t)ntok * 48);         // 1024*128 f16 (256 KB)
  _Float16* A1f     = (_Float16*)(ws + (size_t)ntok * 48 + 262144);          // 32 KB
  _Float16* A2f     = (_Float16*)(ws + (size_t)ntok * 48 + 262144 + 32768);  // 32 KB

  k0_prep<<<80, 256, 0, stream>>>(routed, compress, w_route, Btf, A1f, A2f);
  k_main<<<ntok / 8, 256, 0, stream>>>(x, A1f, A2f, ce16, gate_ws, ntok);
  k2_gemm<<<(ntok / 64) * 4, 256, 0, stream>>>(Btf, ce16, gate_ws, out, ntok);
}

// Round 12
// 41.087 us; speedup vs baseline: 1.0704x; 1.0704x over previous
//
#include <hip/hip_runtime.h>

// TMoELayer: B=4,T=4096 -> N=16384 tokens, D_IN=1024, D_OUT=1024, E=8, TOP_K=2, R=16
// out[n][o] = sum_k (gate(n,e)*ce[n][r]) * routed[e][o][r], k = e*16+r
// Router logits via split-precision MFMA: W = Whi + Wlo/1024 (f16 pair),
// X = Xhi + Xlo (f16 pair) -> logit = Whi.Xhi + Whi.Xlo + (Wlo.Xhi + Wlo.Xlo)/1024.
// Operand tables pre-layouted in FRAGMENT ORDER: every hot-kernel global load is a
// contiguous/128B-segment wave-load.
constexpr float SCALING = 2.0f;  // alpha/r = 32/16

typedef __attribute__((ext_vector_type(8))) _Float16 half8;
typedef __attribute__((ext_vector_type(4))) _Float16 half4;
typedef __attribute__((ext_vector_type(4))) float    f32x4;

// ---------------- Kernel 0: prep (fragment-order tables) — unchanged from R11
__global__ __launch_bounds__(256) void k0_prep(
    const float* __restrict__ routed, const float* __restrict__ compress,
    const float* __restrict__ w_route, _Float16* __restrict__ Btf,
    _Float16* __restrict__ A1f, _Float16* __restrict__ A2f)
{
  const int bid = blockIdx.x, tid = threadIdx.x;
  if (bid < 64){
    const int f = bid * 256 + tid;          // Btf fragment-slot 0..16383
    const int l = f & 63;
    const int rem = f >> 6;
    const int s = rem & 3, ot = rem >> 2;
    const int c15 = l & 15, kg = l >> 4;
    const int e  = 2 * s + (kg >> 1);
    const int r0 = (kg & 1) * 8;
    const float* src = routed + ((size_t)e * 1024 + ot * 16 + c15) * 16 + r0;
    float4 a = *(const float4*)(src);
    float4 b = *(const float4*)(src + 4);
    half8 h;
    h[0]=(_Float16)a.x; h[1]=(_Float16)a.y; h[2]=(_Float16)a.z; h[3]=(_Float16)a.w;
    h[4]=(_Float16)b.x; h[5]=(_Float16)b.y; h[6]=(_Float16)b.z; h[7]=(_Float16)b.w;
    *(half8*)(Btf + (size_t)f * 8) = h;
  } else if (bid < 72){
    const int t2 = (bid - 64) * 256 + tid;  // A2f fragment 0..2047
    const int l = t2 & 63, s = (t2 >> 6) & 7, wq = t2 >> 9;
    const int c15 = l & 15, kg = l >> 4;
    const float* src = compress + (size_t)c15 * 1024 + wq * 256 + s * 32 + kg * 8;
    float4 a = *(const float4*)(src);
    float4 b = *(const float4*)(src + 4);
    half8 h;
    h[0]=(_Float16)(SCALING*a.x); h[1]=(_Float16)(SCALING*a.y);
    h[2]=(_Float16)(SCALING*a.z); h[3]=(_Float16)(SCALING*a.w);
    h[4]=(_Float16)(SCALING*b.x); h[5]=(_Float16)(SCALING*b.y);
    h[6]=(_Float16)(SCALING*b.z); h[7]=(_Float16)(SCALING*b.w);
    *(half8*)(A2f + (size_t)t2 * 8) = h;
  } else {
    const int t3 = (bid - 72) * 256 + tid;  // A1f fragment 0..2047
    const int l = t3 & 63, s = (t3 >> 6) & 7, wq = t3 >> 9;
    const int c15 = l & 15, kg = l >> 4;
    const int row = (c15 < 8) ? c15 : (c15 - 8);
    const float* src = w_route + (size_t)row * 1024 + wq * 256 + s * 32 + kg * 8;
    float4 a = *(const float4*)(src);
    float4 b = *(const float4*)(src + 4);
    float ws[8] = {a.x, a.y, a.z, a.w, b.x, b.y, b.z, b.w};
    half8 h;
    #pragma unroll
    for (int j = 0; j < 8; ++j){
      _Float16 hi = (_Float16)ws[j];
      h[j] = (c15 < 8) ? hi : (_Float16)((ws[j] - (float)hi) * 1024.f);
    }
    *(half8*)(A1f + (size_t)t3 * 8) = h;
  }
}

// ---------------- Kernel 1: all-MFMA router + ce. WAVE-INDEPENDENT, ZERO BARRIERS.
// One wave = 8 tokens, full K=1024 (32 k-steps, 3 MFMA streams each; B cols 8..15
// unused). Per k-step: coalesced float4 x-load -> wave-private rotating LDS slot
// (in-order DS pipe, compiler lgkmcnt; no __syncthreads) -> fragment read ->
// f16 hi/lo cvt -> 3 MFMA. x prefetched one 4-step group ahead (register dbuf).
__global__ __launch_bounds__(256, 4) void k_main(
    const float* __restrict__ x, const _Float16* __restrict__ A1f,
    const _Float16* __restrict__ A2f, _Float16* __restrict__ ce16,
    float4* __restrict__ gate_ws, int ntok)
{
  __shared__ float buf[4][4][8][36];   // [wave][slot][token][32 dims + pad]: 18.4 KB
  const int tid = threadIdx.x, lane = tid & 63, wv = tid >> 6;
  const int c15 = lane & 15, kg = lane >> 4;
  const int t8 = lane >> 3;            // staging token 0..7
  const int d8 = lane & 7;             // staging dim-quad
  const int n0 = (blockIdx.x * 4 + wv) * 8;   // this wave's 8 tokens

  const float* xw = x + (size_t)n0 * 1024 + (size_t)t8 * 1024 + d8 * 4;

  f32x4 acc1 = {0.f,0.f,0.f,0.f};   // [Whi;Wlo] * Xhi
  f32x4 acc3 = {0.f,0.f,0.f,0.f};   // [Whi;Wlo] * Xlo
  f32x4 acc2 = {0.f,0.f,0.f,0.f};   // (2*compress) * Xhi

  float4 xg[2][4];
  #pragma unroll
  for (int s = 0; s < 4; ++s) xg[0][s] = *(const float4*)(xw + s * 32);

  #pragma unroll
  for (int g = 0; g < 8; ++g){
    const int cur = g & 1;
    if (g < 7){
      #pragma unroll
      for (int s = 0; s < 4; ++s)
        xg[cur ^ 1][s] = *(const float4*)(xw + (g + 1) * 128 + s * 32);
    }
    #pragma unroll
    for (int s = 0; s < 4; ++s){
      const int ks = g * 4 + s;
      // stage this step's x into the wave-private slot (WAR vs prev group's read
      // of the same slot is ordered by the in-order per-wave DS pipe)
      *(f32x4*)&buf[wv][s][t8][d8 * 4] =
          (f32x4){xg[cur][s].x, xg[cur][s].y, xg[cur][s].z, xg[cur][s].w};
      half8 a1 = *(const half8*)(A1f + ((size_t)ks * 64 + lane) * 8);
      half8 a2 = *(const half8*)(A2f + ((size_t)ks * 64 + lane) * 8);
      // fragment: 8 f32 of token (c15&7), k-slice kg*8.. (lanes l and l+8 broadcast)
      f32x4 f0 = *(const f32x4*)&buf[wv][s][c15 & 7][kg * 8];
      f32x4 f1 = *(const f32x4*)&buf[wv][s][c15 & 7][kg * 8 + 4];
      float xs[8] = {f0[0], f0[1], f0[2], f0[3], f1[0], f1[1], f1[2], f1[3]};
      half8 bhi, blo;
      #pragma unroll
      for (int q = 0; q < 8; ++q){
        _Float16 h = (_Float16)xs[q];
        bhi[q] = h;
        blo[q] = (_Float16)(xs[q] - (float)h);
      }
      acc1 = __builtin_amdgcn_mfma_f32_16x16x32_f16(a1, bhi, acc1, 0, 0, 0);
      acc3 = __builtin_amdgcn_mfma_f32_16x16x32_f16(a1, blo, acc3, 0, 0, 0);
      acc2 = __builtin_amdgcn_mfma_f32_16x16x32_f16(a2, bhi, acc2, 0, 0, 0);
    }
  }

  // ---- epilogue (per wave, no cross-wave reduce)
  // ce: D row = r = kg*4+v, col = token = c15 (c15<8 valid)
  if (c15 < 8){
    half4 hce;
    hce[0]=(_Float16)acc2[0]; hce[1]=(_Float16)acc2[1];
    hce[2]=(_Float16)acc2[2]; hce[3]=(_Float16)acc2[3];
    *(half4*)(ce16 + (size_t)(n0 + c15) * 16 + kg * 4) = hce;
  }
  // logits: rows 0..7 (kg 0/1) pick up Wlo rows 8..15 from lane+32
  float lg[4];
  #pragma unroll
  for (int v = 0; v < 4; ++v){
    float wlo_xhi = __shfl_xor(acc1[v], 32, 64);
    float wlo_xlo = __shfl_xor(acc3[v], 32, 64);
    lg[v] = acc1[v] + acc3[v] + (wlo_xhi + wlo_xlo) * (1.0f / 1024.0f);
  }
  float l8[8];
  #pragma unroll
  for (int v = 0; v < 4; ++v){
    l8[v]     = lg[v];
    l8[4 + v] = __shfl_xor(lg[v], 16, 64);
  }
  if (lane < 8 && n0 + lane < ntok){
    float v0 = l8[0]; int e0 = 0;
    #pragma unroll
    for (int e = 1; e < 8; ++e) if (l8[e] > v0){ v0 = l8[e]; e0 = e; }
    float v1 = -3.402823466e38f; int e1 = 0;
    #pragma unroll
    for (int e = 0; e < 8; ++e) if (e != e0 && l8[e] > v1){ v1 = l8[e]; e1 = e; }
    float ex  = __expf(v1 - v0);
    float inv = 1.0f / (1.0f + ex);
    gate_ws[n0 + lane] = make_float4(__int_as_float(e0), __int_as_float(e1),
                                     inv, ex * inv);
  }
}

// ---------------- Kernel 2: out = (gate⊙ce) @ Bt^T — unchanged from R10
__global__ __launch_bounds__(256, 4) void k2_gemm(
    const _Float16* __restrict__ Btf, const _Float16* __restrict__ ce16,
    const float4* __restrict__ gate_ws, float* __restrict__ out, int ntok)
{
  __shared__ float tbuf[4][2][16][68];      // per-wave double-buffered, +16B row pad
  const int tid = threadIdx.x, lane = tid & 63, wv = tid >> 6;
  const int c15 = lane & 15, kg = lane >> 4;
  const int bn = blockIdx.x & 3;          // o-chunk of 256
  const int tg = blockIdx.x >> 2;         // token group of 64
  const int o0w = bn * 256 + wv * 64;

  half8 bt[4][4];
  #pragma unroll
  for (int nc = 0; nc < 4; ++nc){
    const int ot = bn * 16 + wv * 4 + nc;
    #pragma unroll
    for (int s = 0; s < 4; ++s)
      bt[nc][s] = *(const half8*)(Btf + ((size_t)(ot * 4 + s) * 64 + lane) * 8);
  }

  int tok = tg * 64 + c15;
  half8  ce_n = *(const half8*)(ce16 + (size_t)tok * 16 + (kg & 1) * 8);
  float4 gt_n = gate_ws[tok];

  #pragma unroll
  for (int i = 0; i < 4; ++i){
    half8 ce_c = ce_n;  float4 gt_c = gt_n;
    if (i < 3){
      const int tok2 = tg * 64 + (i + 1) * 16 + c15;
      ce_n = *(const half8*)(ce16 + (size_t)tok2 * 16 + (kg & 1) * 8);
      gt_n = gate_ws[tok2];
    }
    const int e0 = __float_as_int(gt_c.x), e1 = __float_as_int(gt_c.y);
    const int eb = kg >> 1;

    f32x4 acc[4] = {{0.f,0.f,0.f,0.f},{0.f,0.f,0.f,0.f},
                    {0.f,0.f,0.f,0.f},{0.f,0.f,0.f,0.f}};
    #pragma unroll
    for (int s = 0; s < 4; ++s){
      const int e = 2 * s + eb;           // expert of k-range [s*32+kg*8, +8)
      float sc = (e == e0) ? gt_c.z : ((e == e1) ? gt_c.w : 0.f);
      _Float16 sh = (_Float16)sc;
      half8 bfr;
      #pragma unroll
      for (int q = 0; q < 8; ++q) bfr[q] = ce_c[q] * sh;
      #pragma unroll
      for (int nc = 0; nc < 4; ++nc)
        acc[nc] = __builtin_amdgcn_mfma_f32_16x16x32_f16(bt[nc][s], bfr, acc[nc], 0, 0, 0);
    }
    #pragma unroll
    for (int nc = 0; nc < 4; ++nc)
      *(f32x4*)&tbuf[wv][i & 1][c15][nc * 16 + kg * 4] = acc[nc];
    const int n0i = tg * 64 + i * 16;
    #pragma unroll
    for (int p = 0; p < 4; ++p){
      const int row = p * 4 + kg;         // token-local row
      float4 v = *(const float4*)&tbuf[wv][i & 1][row][c15 * 4];
      *(float4*)(out + (size_t)(n0i + row) * 1024 + o0w + c15 * 4) = v;
    }
  }
}

extern "C" void kernel_launch(void* const* d_in, const int* in_sizes, int n_in,
                              void* d_out, int out_size, void* d_ws, size_t ws_size,
                              hipStream_t stream)
{
  const float* x        = (const float*)d_in[0];
  const float* w_route  = (const float*)d_in[1];
  const float* compress = (const float*)d_in[2];
  const float* routed   = (const float*)d_in[3];
  float* out = (float*)d_out;

  const int ntok = in_sizes[0] / 1024;   // 16384 (B*T)
  char* ws = (char*)d_ws;
  _Float16* ce16    = (_Float16*)ws;                               // ntok*16 f16  (512 KB)
  float4*   gate_ws = (float4*)(ws + (size_t)ntok * 32);           // ntok*16 B    (256 KB)
  _Float16* Btf     = (_Float16*)(ws + (size_t)ntok * 48);         // 1024*128 f16 (256 KB)
  _Float16* A1f     = (_Float16*)(ws + (size_t)ntok * 48 + 262144);          // 32 KB
  _Float16* A2f     = (_Float16*)(ws + (size_t)ntok * 48 + 262144 + 32768);  // 32 KB

  k0_prep<<<80, 256, 0, stream>>>(routed, compress, w_route, Btf, A1f, A2f);
  k_main<<<ntok / 32, 256, 0, stream>>>(x, A1f, A2f, ce16, gate_ws, ntok);
  k2_gemm<<<(ntok / 64) * 4, 256, 0, stream>>>(Btf, ce16, gate_ws, out, ntok);
}

// Round 13
// 36.832 us; speedup vs baseline: 1.1941x; 1.1155x over previous
//
#include <hip/hip_runtime.h>

// TMoELayer: B=4,T=4096 -> N=16384 tokens, D_IN=1024, D_OUT=1024, E=8, TOP_K=2, R=16
// out[n][o] = sum_k (gate(n,e)*ce[n][r]) * routed[e][o][r], k = e*16+r
// Router logits via split-precision MFMA: W = Whi + Wlo/1024 (f16 pair),
// X = Xhi + Xlo (f16 pair) -> logit = Whi.Xhi + Whi.Xlo + (Wlo.Xhi + Wlo.Xlo)/1024.
// FUSED: phase A (wave-independent router+ce, zero barriers) -> LDS -> one barrier
// -> phase B (expert combine over all 4 o-chunks, register-resident Bt fragments).
constexpr float SCALING = 2.0f;  // alpha/r = 32/16

typedef __attribute__((ext_vector_type(8))) _Float16 half8;
typedef __attribute__((ext_vector_type(4))) _Float16 half4;
typedef __attribute__((ext_vector_type(4))) float    f32x4;

// ---------------- Kernel 0: prep (fragment-order tables) — unchanged from R12
__global__ __launch_bounds__(256) void k0_prep(
    const float* __restrict__ routed, const float* __restrict__ compress,
    const float* __restrict__ w_route, _Float16* __restrict__ Btf,
    _Float16* __restrict__ A1f, _Float16* __restrict__ A2f)
{
  const int bid = blockIdx.x, tid = threadIdx.x;
  if (bid < 64){
    const int f = bid * 256 + tid;          // Btf fragment-slot 0..16383
    const int l = f & 63;
    const int rem = f >> 6;
    const int s = rem & 3, ot = rem >> 2;
    const int c15 = l & 15, kg = l >> 4;
    const int e  = 2 * s + (kg >> 1);
    const int r0 = (kg & 1) * 8;
    const float* src = routed + ((size_t)e * 1024 + ot * 16 + c15) * 16 + r0;
    float4 a = *(const float4*)(src);
    float4 b = *(const float4*)(src + 4);
    half8 h;
    h[0]=(_Float16)a.x; h[1]=(_Float16)a.y; h[2]=(_Float16)a.z; h[3]=(_Float16)a.w;
    h[4]=(_Float16)b.x; h[5]=(_Float16)b.y; h[6]=(_Float16)b.z; h[7]=(_Float16)b.w;
    *(half8*)(Btf + (size_t)f * 8) = h;
  } else if (bid < 72){
    const int t2 = (bid - 64) * 256 + tid;  // A2f fragment 0..2047
    const int l = t2 & 63, s = (t2 >> 6) & 7, wq = t2 >> 9;
    const int c15 = l & 15, kg = l >> 4;
    const float* src = compress + (size_t)c15 * 1024 + wq * 256 + s * 32 + kg * 8;
    float4 a = *(const float4*)(src);
    float4 b = *(const float4*)(src + 4);
    half8 h;
    h[0]=(_Float16)(SCALING*a.x); h[1]=(_Float16)(SCALING*a.y);
    h[2]=(_Float16)(SCALING*a.z); h[3]=(_Float16)(SCALING*a.w);
    h[4]=(_Float16)(SCALING*b.x); h[5]=(_Float16)(SCALING*b.y);
    h[6]=(_Float16)(SCALING*b.z); h[7]=(_Float16)(SCALING*b.w);
    *(half8*)(A2f + (size_t)t2 * 8) = h;
  } else {
    const int t3 = (bid - 72) * 256 + tid;  // A1f fragment 0..2047
    const int l = t3 & 63, s = (t3 >> 6) & 7, wq = t3 >> 9;
    const int c15 = l & 15, kg = l >> 4;
    const int row = (c15 < 8) ? c15 : (c15 - 8);
    const float* src = w_route + (size_t)row * 1024 + wq * 256 + s * 32 + kg * 8;
    float4 a = *(const float4*)(src);
    float4 b = *(const float4*)(src + 4);
    float ws[8] = {a.x, a.y, a.z, a.w, b.x, b.y, b.z, b.w};
    half8 h;
    #pragma unroll
    for (int j = 0; j < 8; ++j){
      _Float16 hi = (_Float16)ws[j];
      h[j] = (c15 < 8) ? hi : (_Float16)((ws[j] - (float)hi) * 1024.f);
    }
    *(half8*)(A1f + (size_t)t3 * 8) = h;
  }
}

// ---------------- Fused kernel: block = 32 tokens, 4 waves, grid 512.
// Phase A: wave = 8 tokens, full K, zero barriers (R12 k_main), results -> LDS.
// One __syncthreads. Phase B: k2 structure looped over 4 o-chunks, Bt fragments
// register-resident per o-chunk, out stores via per-wave LDS transpose (no barriers).
__global__ __launch_bounds__(256, 4) void k_fused(
    const float* __restrict__ x, const _Float16* __restrict__ A1f,
    const _Float16* __restrict__ A2f, const _Float16* __restrict__ Btf,
    float* __restrict__ out, int ntok)
{
  __shared__ __align__(16) char smem[34816];   // phase-A buf ALIASES phase-B tbuf
  __shared__ _Float16 ce_lds[32][24];          // 1.5 KB, 48B rows (16B-aligned reads)
  __shared__ float    gate_lds[32][5];         // 640 B, 5-word rows (conflict-free)
  float (*buf)[4][8][36]  = (float(*)[4][8][36])smem;    // [wave][slot][tok][36]
  float (*tbuf)[2][16][68] = (float(*)[2][16][68])smem;  // [wave][dbuf][16][68]

  const int tid = threadIdx.x, lane = tid & 63, wv = tid >> 6;
  const int c15 = lane & 15, kg = lane >> 4;
  const int t8 = lane >> 3, d8 = lane & 7;
  const int n0 = blockIdx.x * 32;
  const int n0w = n0 + wv * 8;                 // this wave's 8 tokens

  // ======== phase A (identical math to R12 k_main) ========
  {
    const float* xw = x + (size_t)(n0w + t8) * 1024 + d8 * 4;
    f32x4 acc1 = {0.f,0.f,0.f,0.f};   // [Whi;Wlo] * Xhi
    f32x4 acc3 = {0.f,0.f,0.f,0.f};   // [Whi;Wlo] * Xlo
    f32x4 acc2 = {0.f,0.f,0.f,0.f};   // (2*compress) * Xhi
    float4 xg[2][4];
    #pragma unroll
    for (int s = 0; s < 4; ++s) xg[0][s] = *(const float4*)(xw + s * 32);
    #pragma unroll
    for (int g = 0; g < 8; ++g){
      const int cur = g & 1;
      if (g < 7){
        #pragma unroll
        for (int s = 0; s < 4; ++s)
          xg[cur ^ 1][s] = *(const float4*)(xw + (g + 1) * 128 + s * 32);
      }
      #pragma unroll
      for (int s = 0; s < 4; ++s){
        const int ks = g * 4 + s;
        *(f32x4*)&buf[wv][s][t8][d8 * 4] =
            (f32x4){xg[cur][s].x, xg[cur][s].y, xg[cur][s].z, xg[cur][s].w};
        half8 a1 = *(const half8*)(A1f + ((size_t)ks * 64 + lane) * 8);
        half8 a2 = *(const half8*)(A2f + ((size_t)ks * 64 + lane) * 8);
        f32x4 f0 = *(const f32x4*)&buf[wv][s][c15 & 7][kg * 8];
        f32x4 f1 = *(const f32x4*)&buf[wv][s][c15 & 7][kg * 8 + 4];
        float xs[8] = {f0[0], f0[1], f0[2], f0[3], f1[0], f1[1], f1[2], f1[3]};
        half8 bhi, blo;
        #pragma unroll
        for (int q = 0; q < 8; ++q){
          _Float16 h = (_Float16)xs[q];
          bhi[q] = h;
          blo[q] = (_Float16)(xs[q] - (float)h);
        }
        acc1 = __builtin_amdgcn_mfma_f32_16x16x32_f16(a1, bhi, acc1, 0, 0, 0);
        acc3 = __builtin_amdgcn_mfma_f32_16x16x32_f16(a1, blo, acc3, 0, 0, 0);
        acc2 = __builtin_amdgcn_mfma_f32_16x16x32_f16(a2, bhi, acc2, 0, 0, 0);
      }
    }
    // epilogue -> LDS (block-local rows)
    if (c15 < 8){
      half4 hce;
      hce[0]=(_Float16)acc2[0]; hce[1]=(_Float16)acc2[1];
      hce[2]=(_Float16)acc2[2]; hce[3]=(_Float16)acc2[3];
      *(half4*)&ce_lds[wv * 8 + c15][kg * 4] = hce;
    }
    float lg[4];
    #pragma unroll
    for (int v = 0; v < 4; ++v){
      float wlo_xhi = __shfl_xor(acc1[v], 32, 64);
      float wlo_xlo = __shfl_xor(acc3[v], 32, 64);
      lg[v] = acc1[v] + acc3[v] + (wlo_xhi + wlo_xlo) * (1.0f / 1024.0f);
    }
    float l8[8];
    #pragma unroll
    for (int v = 0; v < 4; ++v){
      l8[v]     = lg[v];
      l8[4 + v] = __shfl_xor(lg[v], 16, 64);
    }
    if (lane < 8){
      float v0 = l8[0]; int e0 = 0;
      #pragma unroll
      for (int e = 1; e < 8; ++e) if (l8[e] > v0){ v0 = l8[e]; e0 = e; }
      float v1 = -3.402823466e38f; int e1 = 0;
      #pragma unroll
      for (int e = 0; e < 8; ++e) if (e != e0 && l8[e] > v1){ v1 = l8[e]; e1 = e; }
      float ex  = __expf(v1 - v0);
      float inv = 1.0f / (1.0f + ex);
      gate_lds[wv * 8 + lane][0] = __int_as_float(e0);
      gate_lds[wv * 8 + lane][1] = __int_as_float(e1);
      gate_lds[wv * 8 + lane][2] = inv;
      gate_lds[wv * 8 + lane][3] = ex * inv;
    }
  }
  __syncthreads();   // ce/gate published; phase-A buf dead -> tbuf may reuse smem

  // ======== phase B: out[32 tok][1024 o] over 4 o-chunks ========
  #pragma unroll 1
  for (int bn = 0; bn < 4; ++bn){
    const int o0w = bn * 256 + wv * 64;
    half8 bt[4][4];
    #pragma unroll
    for (int nc = 0; nc < 4; ++nc){
      const int ot = bn * 16 + wv * 4 + nc;
      #pragma unroll
      for (int s = 0; s < 4; ++s)
        bt[nc][s] = *(const half8*)(Btf + ((size_t)(ot * 4 + s) * 64 + lane) * 8);
    }
    #pragma unroll
    for (int i = 0; i < 2; ++i){
      const int tl = i * 16 + c15;                  // block-local token
      half8 ce_c = *(const half8*)&ce_lds[tl][(kg & 1) * 8];
      const int e0 = __float_as_int(gate_lds[tl][0]);
      const int e1 = __float_as_int(gate_lds[tl][1]);
      const float w0 = gate_lds[tl][2], w1 = gate_lds[tl][3];
      const int eb = kg >> 1;

      f32x4 acc[4] = {{0.f,0.f,0.f,0.f},{0.f,0.f,0.f,0.f},
                      {0.f,0.f,0.f,0.f},{0.f,0.f,0.f,0.f}};
      #pragma unroll
      for (int s = 0; s < 4; ++s){
        const int e = 2 * s + eb;          // expert of k-range [s*32+kg*8, +8)
        float sc = (e == e0) ? w0 : ((e == e1) ? w1 : 0.f);
        _Float16 sh = (_Float16)sc;
        half8 bfr;
        #pragma unroll
        for (int q = 0; q < 8; ++q) bfr[q] = ce_c[q] * sh;
        #pragma unroll
        for (int nc = 0; nc < 4; ++nc)
          acc[nc] = __builtin_amdgcn_mfma_f32_16x16x32_f16(bt[nc][s], bfr, acc[nc], 0, 0, 0);
      }
      const int db = (bn * 2 + i) & 1;
      #pragma unroll
      for (int nc = 0; nc < 4; ++nc)
        *(f32x4*)&tbuf[wv][db][c15][nc * 16 + kg * 4] = acc[nc];
      // per-wave in-order DS pipe: reads below wait via lgkmcnt, no barrier.
      const int n0i = n0 + i * 16;
      #pragma unroll
      for (int p = 0; p < 4; ++p){
        const int row = p * 4 + kg;        // token-local row
        float4 v = *(const float4*)&tbuf[wv][db][row][c15 * 4];
        *(float4*)(out + (size_t)(n0i + row) * 1024 + o0w + c15 * 4) = v;
      }
    }
  }
}

extern "C" void kernel_launch(void* const* d_in, const int* in_sizes, int n_in,
                              void* d_out, int out_size, void* d_ws, size_t ws_size,
                              hipStream_t stream)
{
  const float* x        = (const float*)d_in[0];
  const float* w_route  = (const float*)d_in[1];
  const float* compress = (const float*)d_in[2];
  const float* routed   = (const float*)d_in[3];
  float* out = (float*)d_out;

  const int ntok = in_sizes[0] / 1024;   // 16384 (B*T)
  char* ws = (char*)d_ws;
  _Float16* Btf = (_Float16*)ws;                   // 1024*128 f16 (256 KB)
  _Float16* A1f = (_Float16*)(ws + 262144);        // 16*1024 f16  (32 KB)
  _Float16* A2f = (_Float16*)(ws + 262144 + 32768);// 16*1024 f16  (32 KB)

  k0_prep<<<80, 256, 0, stream>>>(routed, compress, w_route, Btf, A1f, A2f);
  k_fused<<<ntok / 32, 256, 0, stream>>>(x, A1f, A2f, Btf, out, ntok);
}